// Round 17
// baseline (134.062 us; speedup 1.0000x reference)
//
#include <hip/hip_runtime.h>
#include <hip/hip_bf16.h>
#include <stdint.h>

typedef int i32x4 __attribute__((ext_vector_type(4)));

#define GLL(gp, lp) __builtin_amdgcn_global_load_lds( \
    (const __attribute__((address_space(1))) void*)(gp), \
    (__attribute__((address_space(3))) void*)(lp), 16, 0, 0)

// ---------------- exact-math helpers (match XLA/np f32 semantics) -----------

__device__ __forceinline__ float xla_erf(float x) {
#pragma clang fp contract(off)
  x = fminf(3.832506856900711f, fmaxf(-3.832506856900711f, x));
  float x2 = x * x;
  float p = -2.72614225801306e-10f;
  p = p * x2 + 2.77068142495902e-08f;
  p = p * x2 + -2.10102402082508e-06f;
  p = p * x2 + -5.69250639462346e-05f;
  p = p * x2 + -7.34990630326855e-04f;
  p = p * x2 + -2.95459980854025e-03f;
  p = p * x2 + -1.60960333262415e-02f;
  p = x * p;
  float q = -1.45660718464996e-05f;
  q = q * x2 + -2.13374055278905e-04f;
  q = q * x2 + -1.68282697438203e-03f;
  q = q * x2 + -7.37332916720468e-03f;
  q = q * x2 + -1.42647390514189e-02f;
  return p / q;
}

__device__ __forceinline__ float gelu_exact(float x) {
#pragma clang fp contract(off)
  float t = x / 1.41421356237309504880f;
  float e = xla_erf(t);
  float u = e + 1.0f;
  float v = x * u;
  return v * 0.5f;
}

__device__ __forceinline__ float epi_scale(float iacc, float sc, float b) {
#pragma clang fp contract(off)
  float v = iacc * sc;
  v = v + b;
  return v;
}

__device__ __forceinline__ int quant1(float x, float scale) {
#pragma clang fp contract(off)
  float t = x / scale;
  t = rintf(t);
  t = fmaxf(-8.0f, fminf(7.0f, t));
  return (int)t;
}

// tiled i8 layout (round-11-validated): byte (row m, col c) at
// tile ((m>>4)*kt + (c>>6))*1024 + ((m&15) | (((c>>4)&3)<<4))*16 + (c&15)
__device__ __forceinline__ long tiled_off(long m, long c, int kt) {
  return (((m >> 4) * kt + (c >> 6)) << 10) +
         ((((m & 15) | (((c >> 4) & 3) << 4))) << 4) + (c & 15);
}

// ---------------- small kernels ---------------------------------------------

__global__ void init_kernel(unsigned* slots) {
  if (threadIdx.x < 4) slots[threadIdx.x] = 0u;
}

__global__ void absmax3(const float* __restrict__ p0, long n0,
                        const float* __restrict__ p1, long n1,
                        const float* __restrict__ p2, long n2,
                        unsigned* __restrict__ slots) {
  __shared__ float red[4];
  const int t = blockIdx.y;
  const float4* p = (const float4*)(t == 0 ? p0 : (t == 1 ? p1 : p2));
  const long n4 = (t == 0 ? n0 : (t == 1 ? n1 : n2));
  float m = 0.0f;
  long i = (long)blockIdx.x * blockDim.x + threadIdx.x;
  const long stride = (long)gridDim.x * blockDim.x;
  for (; i < n4; i += stride) {
    float4 v = p[i];
    m = fmaxf(m, fmaxf(fmaxf(fabsf(v.x), fabsf(v.y)), fmaxf(fabsf(v.z), fabsf(v.w))));
  }
  for (int o = 32; o > 0; o >>= 1) m = fmaxf(m, __shfl_xor(m, o));
  if ((threadIdx.x & 63) == 0) red[threadIdx.x >> 6] = m;
  __syncthreads();
  if (threadIdx.x == 0) {
    m = fmaxf(fmaxf(red[0], red[1]), fmaxf(red[2], red[3]));
    atomicMax(slots + t, __float_as_uint(m));
  }
}

// one dispatch for all three input quantizations (blockIdx.y selects tensor).
__global__ void quant3(const float* __restrict__ in0, const float* __restrict__ in1,
                       const float* __restrict__ in2,
                       int Rp0, int Rp1, int Rp2, int R0, int R1, int R2,
                       int C0, int C1, int C2, int kt0, int kt1, int kt2,
                       const unsigned* __restrict__ slots,
                       char* __restrict__ o0, char* __restrict__ o1,
                       char* __restrict__ o2) {
  const int y = blockIdx.y;
  const float* in = (y == 0 ? in0 : (y == 1 ? in1 : in2));
  char* qout = (y == 0 ? o0 : (y == 1 ? o1 : o2));
  const int Rpad = (y == 0 ? Rp0 : (y == 1 ? Rp1 : Rp2));
  const int R = (y == 0 ? R0 : (y == 1 ? R1 : R2));
  const int C = (y == 0 ? C0 : (y == 1 ? C1 : C2));
  const int kt = (y == 0 ? kt0 : (y == 1 ? kt1 : kt2));
  const int sign = (y == 0 ? 1 : -1);
  const int segs_per_row = C >> 8;
  const int seg = blockIdx.x * 4 + (threadIdx.x >> 6);
  if (seg >= Rpad * segs_per_row) return;
  const int lane = threadIdx.x & 63;
  const int r = seg / segs_per_row;
  const int s = seg - r * segs_per_row;
  const float scale = fmaxf(__uint_as_float(slots[y]) / 7.0f, 1e-8f);
  const long n = (long)s * 256 + lane * 4;
  int mask = 0;
  unsigned pk = 0u;
  if (r < R) {
    const size_t base = (size_t)r * C + n;
    float4 v = *(const float4*)(in + base);
    int q0 = quant1(v.x, scale);
    int q1 = quant1(v.y, scale);
    int q2 = quant1(v.z, scale);
    int q3 = quant1(v.w, scale);
    pk = (q0 & 0xff) | ((q1 & 0xff) << 8) | ((q2 & 0xff) << 16) |
         ((unsigned)(q3 & 0xff) << 24);
    mask = q0 & q1 & q2 & q3 & 15;
  }
  *(unsigned*)(qout + tiled_off(r, n, kt)) = pk;
  for (int o = 32; o > 0; o >>= 1) mask &= __shfl_xor(mask, o);
  if (lane == 0)
    qout[tiled_off(r, C + s, kt)] = (char)(sign * ((mask & 7) - (mask & 8)));
  const int padw = kt * 64 - C - segs_per_row;
  if (s == 0 && lane < padw)
    qout[tiled_off(r, C + segs_per_row + lane, kt)] = 0;
}

// ---------------- GEMM core: 64(M)x128(N) block, 2x2 waves of 32x64 ----------
// 8 MFMA + 6 ds_read per wave-iteration (2x the work per barrier of the 64x64
// version). Triple-buffered LDS depth-2 prefetch, 3 GLL/wave/stage (1 A + 2 B)
// -> vmcnt steady 9 outstanding, wait(6); tail (3), (0). LDS 36KB -> 4 blk/CU.
// MODE 0: stores gelu(acc*sc+b1) f32 (computed once) + fused block-max.
// MODE 1: split-K, stores raw acc (exact ints).
template <int MODE>
__global__ __launch_bounds__(256) void gemm_frag(
    const char* __restrict__ A, const char* __restrict__ B,
    int ktA, int mtiles, int kbase, int krem,
    i32x4* __restrict__ frag, long cslots,
    const float* __restrict__ bias, const unsigned* __restrict__ slots,
    int Mstore, float* __restrict__ pmax) {
  __shared__ char Abuf[3][4096];   // 64 rows  x 64B k-slice
  __shared__ char Bbuf[3][8192];   // 128 rows x 64B k-slice
  const int tid = threadIdx.x;
  const int lane = tid & 63;
  const int wv = tid >> 6;

  // bijective XCD-aware swizzle (m204)
  const int nwg = gridDim.x;
  const int q8 = nwg >> 3, r8 = nwg & 7;
  const int xcd = blockIdx.x & 7, idx = blockIdx.x >> 3;
  const int sw = (xcd < r8 ? xcd * (q8 + 1) : r8 * (q8 + 1) + (xcd - r8) * q8) + idx;
  const int bm = sw % mtiles;
  const int bn = sw / mtiles;
  const long m0 = (long)bm * 64;
  const long n0 = (long)bn * 128;
  const int chunk = blockIdx.y;
  const int k_begin = chunk * kbase + min(chunk, krem);  // BK=64 tile units
  const int k_iters = kbase + (chunk < krem ? 1 : 0);

  const int wm = wv >> 1, wn = wv & 1;   // wave tile: 32(M) x 64(N)
  const int lr = lane & 15, kg = lane >> 4;

  // staging: wave wv owns A row-tile wv and B row-tiles 2wv, 2wv+1
  const char* gA  = A + (((long)(m0 >> 4) + wv) * ktA + k_begin) * 1024 + lane * 16;
  const char* gB0 = B + (((long)(n0 >> 4) + 2 * wv) * ktA + k_begin) * 1024 + lane * 16;
  const char* gB1 = gB0 + (long)ktA * 1024;

#define STAGE(buf, kk) do { \
    GLL(gA + (long)(kk) * 1024, (char*)Abuf + (buf) * 4096 + wv * 1024); \
    GLL(gB0 + (long)(kk) * 1024, (char*)Bbuf + (buf) * 8192 + (2 * wv) * 1024); \
    GLL(gB1 + (long)(kk) * 1024, (char*)Bbuf + (buf) * 8192 + (2 * wv + 1) * 1024); \
  } while (0)

  i32x4 acc[2][4] = {};

  STAGE(0, 0);
  if (k_iters > 1) STAGE(1, 1);
  int cur = 0;
  for (int kt = 0; kt < k_iters; ++kt) {
    if (kt + 2 < k_iters) {
      const int nb = cur == 0 ? 2 : (cur == 1 ? 0 : 1);  // (cur+2)%3
      STAGE(nb, kt + 2);
      asm volatile("s_waitcnt vmcnt(6)" ::: "memory");  // cur's 3 GLLs landed
    } else if (kt + 1 < k_iters) {
      asm volatile("s_waitcnt vmcnt(3)" ::: "memory");
    } else {
      asm volatile("s_waitcnt vmcnt(0)" ::: "memory");
    }
    __builtin_amdgcn_s_barrier();  // all waves' cur stages visible
    const char* pa = (const char*)Abuf + cur * 4096;
    const char* pb = (const char*)Bbuf + cur * 8192;
    i32x4 av[2], bv[4];
#pragma unroll
    for (int f = 0; f < 2; ++f)
      av[f] = *(const i32x4*)(pa + (wm * 2 + f) * 1024 + lane * 16);
#pragma unroll
    for (int f = 0; f < 4; ++f)
      bv[f] = *(const i32x4*)(pb + (wn * 4 + f) * 1024 + lane * 16);
#pragma unroll
    for (int fa = 0; fa < 2; ++fa)
#pragma unroll
      for (int fb = 0; fb < 4; ++fb)
        acc[fa][fb] = __builtin_amdgcn_mfma_i32_16x16x64_i8(av[fa], bv[fb], acc[fa][fb], 0, 0, 0);
    __builtin_amdgcn_s_barrier();  // reads done before buf re-staged
    cur = cur == 2 ? 0 : cur + 1;
  }
#undef STAGE

  // 2048 lanes per block: wave wv, frag (fa*4+fb), lane
  i32x4* po = frag + (long)chunk * cslots + (((long)sw * 4 + wv) * 8) * 64 + lane;

  if (MODE == 0) {
    __shared__ float red[4];
    const float sa = fmaxf(__uint_as_float(slots[0]) / 7.0f, 1e-8f);
    const float sb = fmaxf(__uint_as_float(slots[1]) / 7.0f, 1e-8f);
    const float sc = sa * sb;
    float bl[4];
#pragma unroll
    for (int fb = 0; fb < 4; ++fb) bl[fb] = bias[n0 + wn * 64 + fb * 16 + lr];
    float hmax = 0.0f;
#pragma unroll
    for (int fa = 0; fa < 2; ++fa) {
#pragma unroll
      for (int fb = 0; fb < 4; ++fb) {
        float4 g;
#pragma unroll
        for (int rr = 0; rr < 4; ++rr) {
          float h = gelu_exact(epi_scale((float)acc[fa][fb][rr], sc, bl[fb]));
          (&g.x)[rr] = h;
          const long m = m0 + wm * 32 + fa * 16 + kg * 4 + rr;
          if (m < Mstore) hmax = fmaxf(hmax, fabsf(h));
        }
        *(float4*)(po + (fa * 4 + fb) * 64) = g;  // gelu(h) f32, coalesced
      }
    }
    for (int o = 32; o > 0; o >>= 1) hmax = fmaxf(hmax, __shfl_xor(hmax, o));
    if ((tid & 63) == 0) red[tid >> 6] = hmax;
    __syncthreads();
    if (tid == 0)
      pmax[blockIdx.x] = fmaxf(fmaxf(red[0], red[1]), fmaxf(red[2], red[3]));
  } else {
#pragma unroll
    for (int fa = 0; fa < 2; ++fa)
#pragma unroll
      for (int fb = 0; fb < 4; ++fb)
        po[(fa * 4 + fb) * 64] = acc[fa][fb];  // raw exact-int partials
  }
}

// one block reduces pmax[0..n) -> slots[3] (single writer, no atomic)
__global__ void epi1max_final(const float* __restrict__ pmax, int n,
                              unsigned* __restrict__ slots) {
  __shared__ float red[4];
  float m = 0.0f;
  for (int i = threadIdx.x; i < n; i += 256) m = fmaxf(m, pmax[i]);
  for (int o = 32; o > 0; o >>= 1) m = fmaxf(m, __shfl_xor(m, o));
  if ((threadIdx.x & 63) == 0) red[threadIdx.x >> 6] = m;
  __syncthreads();
  if (threadIdx.x == 0)
    slots[3] = __float_as_uint(fmaxf(fmaxf(red[0], red[1]), fmaxf(red[2], red[3])));
}

// decode: fragment-slot t -> (m base, n); matches gemm_frag 64x128 geometry
struct Dec { long mb; long n; };
__device__ __forceinline__ Dec frag_decode(long t, int mtiles) {
  const int slot = (int)(t >> 11);       // 2048 lanes per block
  const int r = (int)t & 2047;
  const int wv = r >> 9, fafb = (r >> 6) & 7, lane = r & 63;
  const int fa = fafb >> 2, fb = fafb & 3;
  const int wm = wv >> 1, wn = wv & 1;
  const int kg = lane >> 4, lr = lane & 15;
  const int bm = slot % mtiles, bn = slot / mtiles;
  Dec d;
  d.mb = (long)bm * 64 + wm * 32 + fa * 16 + kg * 4;   // rows mb..mb+3
  d.n = (long)bn * 128 + wn * 64 + fb * 16 + lr;
  return d;
}

// quantize pre-computed gelu(h) -> hqt (tiled); pad rows explicit zeros.
__global__ void epi1quant(const float* __restrict__ gfrag, long nfrag, int mtiles,
                          int Mstore, const unsigned* __restrict__ slots,
                          char* __restrict__ hqt, int ktH) {
  const long t = (long)blockIdx.x * 256 + threadIdx.x;
  if (t >= nfrag) return;
  const float sh = fmaxf(__uint_as_float(slots[3]) / 7.0f, 1e-8f);
  Dec d = frag_decode(t, mtiles);
  float4 v = ((const float4*)gfrag)[t];
#pragma unroll
  for (int rr = 0; rr < 4; ++rr) {
    const long m = d.mb + rr;
    char q = 0;
    if (m < Mstore) q = (char)quant1((&v.x)[rr], sh);
    hqt[tiled_off(m, d.n, ktH)] = q;
  }
}

// one block per row of hqt: per-seg AND-masks -> corr col C+seg, zero tail.
__global__ void mask_fill_tiled(char* __restrict__ hqt, int ktH, int C, int nseg) {
  const long r = blockIdx.x;
  const int tid = threadIdx.x;
  const int lane = tid & 63, w = tid >> 6;
  int mk[3];
#pragma unroll
  for (int j = 0; j < 3; ++j) {
    const int seg = j * 4 + w;
    const long n = (long)seg * 256 + lane * 4;
    unsigned v = *(const unsigned*)(hqt + tiled_off(r, n, ktH));
    mk[j] = (int)(v & (v >> 8) & (v >> 16) & (v >> 24)) & 15;
  }
#pragma unroll
  for (int j = 0; j < 3; ++j)
    for (int o = 32; o > 0; o >>= 1) mk[j] &= __shfl_xor(mk[j], o);
  if (lane == 0) {
#pragma unroll
    for (int j = 0; j < 3; ++j) {
      const int seg = j * 4 + w;
      hqt[tiled_off(r, C + seg, ktH)] = (char)((mk[j] & 7) - (mk[j] & 8));
    }
  }
  if (tid >= nseg && tid < 64) hqt[tiled_off(r, C + tid, ktH)] = 0;
}

// final epilogue: exact int sum of 6 split-K fragment chunks, scale+bias
__global__ void epi2frag(const i32x4* __restrict__ frag, long cslots, int mtiles,
                         int Mstore, const float* __restrict__ b2,
                         const unsigned* __restrict__ slots,
                         float* __restrict__ out, int ldo) {
  const long t = (long)blockIdx.x * 256 + threadIdx.x;
  if (t >= cslots) return;
  const float sa = fmaxf(__uint_as_float(slots[3]) / 7.0f, 1e-8f);
  const float sb = fmaxf(__uint_as_float(slots[2]) / 7.0f, 1e-8f);
  const float sc = sa * sb;
  Dec d = frag_decode(t, mtiles);
  i32x4 c0 = frag[t];
  i32x4 c1 = frag[t + cslots];
  i32x4 c2 = frag[t + 2 * cslots];
  i32x4 c3 = frag[t + 3 * cslots];
  i32x4 c4 = frag[t + 4 * cslots];
  i32x4 c5 = frag[t + 5 * cslots];
  const float b = b2[d.n];
#pragma unroll
  for (int rr = 0; rr < 4; ++rr) {
    const long m = d.mb + rr;
    if (m < Mstore) {
      int s = ((c0[rr] + c1[rr]) + (c2[rr] + c3[rr])) + (c4[rr] + c5[rr]);
      out[m * (long)ldo + d.n] = epi_scale((float)s, sc, b);
    }
  }
}

// ---------------- launch -----------------------------------------------------

extern "C" void kernel_launch(void* const* d_in, const int* in_sizes, int n_in,
                              void* d_out, int out_size, void* d_ws, size_t ws_size,
                              hipStream_t stream) {
  const float* x  = (const float*)d_in[0];
  const float* w1 = (const float*)d_in[1];
  const float* b1 = (const float*)d_in[2];
  const float* w2 = (const float*)d_in[3];
  const float* b2 = (const float*)d_in[4];
  float* out = (float*)d_out;

  const int Ntok = 16 * 197;  // 3152
  const int Mpad = 3328;      // 52 tiles of 64
  const int D = 768, H = 3072;
  const int KT1 = 13;         // k-tiles (64B) for D + corr
  const int KT2 = 49;         // k-tiles for H + corr
  const int SPLITK = 6;       // 49 = 6*8 + 1
  const int MT = Mpad / 64;   // 52
  const int NB1 = MT * (H / 128);                 // 1248 gemm1 blocks
  const long NF1 = (long)NB1 * 2048;              // GEMM1 fragment lanes
  const long CS2 = (long)MT * (D / 128) * 2048;   // GEMM2 slots per chunk

  char* ws = (char*)d_ws;
  size_t o = 0;
  unsigned* slots = (unsigned*)(ws + o); o += 256;  // [x, w1, w2, h]
  float* pmax = (float*)(ws + o); o += 16384;
  char* xqt  = ws + o; o += (size_t)(Mpad / 16) * KT1 * 1024;
  char* wq1t = ws + o; o += (size_t)(H / 16) * KT1 * 1024;
  char* wq2t = ws + o; o += (size_t)(D / 16) * KT2 * 1024;
  char* hqt  = ws + o; o += (size_t)(Mpad / 16) * KT2 * 1024;
  o = (o + 1023) & ~(size_t)1023;
  i32x4* frag = (i32x4*)(ws + o);
  // gemm1 needs NF1*16 = 40.9MB; gemm2 needs CS2*SPLITK*16 = 61.3MB (reused)
  o += (size_t)CS2 * SPLITK * 16;
  (void)ws_size; (void)in_sizes; (void)n_in; (void)out_size;

  hipLaunchKernelGGL(init_kernel, dim3(1), dim3(64), 0, stream, slots);

  hipLaunchKernelGGL(absmax3, dim3(512, 3), dim3(256), 0, stream,
                     x, (long)Ntok * D / 4, w1, (long)H * D / 4,
                     w2, (long)D * H / 4, slots);

  // one dispatch quantizes x, w1, w2 into fragment-tiled i8
  hipLaunchKernelGGL(quant3, dim3(Mpad * (D / 256) / 4, 3), dim3(256), 0, stream,
                     x, w1, w2, Mpad, H, D, Ntok, H, D, D, D, H,
                     KT1, KT1, KT2, slots, xqt, wq1t, wq2t);

  // layer 1 GEMM: 64x128 tiles, 1248 blocks, stores gelu(h) f32 + block-max
  hipLaunchKernelGGL((gemm_frag<0>), dim3(NB1, 1), dim3(256), 0, stream,
                     xqt, wq1t, KT1, MT, KT1, 0, frag, 0L,
                     b1, slots, Ntok, pmax);
  hipLaunchKernelGGL(epi1max_final, dim3(1), dim3(256), 0, stream,
                     pmax, NB1, slots);

  // quantize gelu(h) -> hqt (tiled, pad rows zeroed inline), then masks+tail
  hipLaunchKernelGGL(epi1quant, dim3((unsigned)(NF1 / 256)), dim3(256), 0, stream,
                     (const float*)frag, NF1, MT, Ntok, slots, hqt, KT2);
  hipLaunchKernelGGL(mask_fill_tiled, dim3(Mpad), dim3(256), 0, stream,
                     hqt, KT2, H, 12);

  // layer 2 GEMM: 64x128 tiles, split-K x6 -> 1872 blocks, raw int partials
  hipLaunchKernelGGL((gemm_frag<1>), dim3(MT * (D / 128), SPLITK), dim3(256), 0, stream,
                     hqt, wq2t, KT2, MT, KT2 / SPLITK, KT2 % SPLITK, frag, CS2,
                     nullptr, nullptr, 0, nullptr);

  hipLaunchKernelGGL(epi2frag, dim3((unsigned)(CS2 / 256)), dim3(256), 0, stream,
                     frag, CS2, MT, Ntok, b2, slots, out, D);
}

// Round 18
// 123.126 us; speedup vs baseline: 1.0888x; 1.0888x over previous
//
#include <hip/hip_runtime.h>
#include <hip/hip_bf16.h>
#include <stdint.h>

typedef int i32x4 __attribute__((ext_vector_type(4)));

#define GLL(gp, lp) __builtin_amdgcn_global_load_lds( \
    (const __attribute__((address_space(1))) void*)(gp), \
    (__attribute__((address_space(3))) void*)(lp), 16, 0, 0)

// ---------------- exact-math helpers (match XLA/np f32 semantics) -----------

__device__ __forceinline__ float xla_erf(float x) {
#pragma clang fp contract(off)
  x = fminf(3.832506856900711f, fmaxf(-3.832506856900711f, x));
  float x2 = x * x;
  float p = -2.72614225801306e-10f;
  p = p * x2 + 2.77068142495902e-08f;
  p = p * x2 + -2.10102402082508e-06f;
  p = p * x2 + -5.69250639462346e-05f;
  p = p * x2 + -7.34990630326855e-04f;
  p = p * x2 + -2.95459980854025e-03f;
  p = p * x2 + -1.60960333262415e-02f;
  p = x * p;
  float q = -1.45660718464996e-05f;
  q = q * x2 + -2.13374055278905e-04f;
  q = q * x2 + -1.68282697438203e-03f;
  q = q * x2 + -7.37332916720468e-03f;
  q = q * x2 + -1.42647390514189e-02f;
  return p / q;
}

__device__ __forceinline__ float gelu_exact(float x) {
#pragma clang fp contract(off)
  float t = x / 1.41421356237309504880f;
  float e = xla_erf(t);
  float u = e + 1.0f;
  float v = x * u;
  return v * 0.5f;
}

__device__ __forceinline__ float epi_scale(float iacc, float sc, float b) {
#pragma clang fp contract(off)
  float v = iacc * sc;
  v = v + b;
  return v;
}

__device__ __forceinline__ int quant1(float x, float scale) {
#pragma clang fp contract(off)
  float t = x / scale;
  t = rintf(t);
  t = fmaxf(-8.0f, fminf(7.0f, t));
  return (int)t;
}

// tiled i8 layout (round-11-validated): byte (row m, col c) at
// tile ((m>>4)*kt + (c>>6))*1024 + ((m&15) | (((c>>4)&3)<<4))*16 + (c&15)
__device__ __forceinline__ long tiled_off(long m, long c, int kt) {
  return (((m >> 4) * kt + (c >> 6)) << 10) +
         ((((m & 15) | (((c >> 4) & 3) << 4))) << 4) + (c & 15);
}

// ---------------- small kernels ---------------------------------------------

__global__ void init_kernel(unsigned* slots) {
  if (threadIdx.x < 4) slots[threadIdx.x] = 0u;
}

__global__ void absmax3(const float* __restrict__ p0, long n0,
                        const float* __restrict__ p1, long n1,
                        const float* __restrict__ p2, long n2,
                        unsigned* __restrict__ slots) {
  __shared__ float red[4];
  const int t = blockIdx.y;
  const float4* p = (const float4*)(t == 0 ? p0 : (t == 1 ? p1 : p2));
  const long n4 = (t == 0 ? n0 : (t == 1 ? n1 : n2));
  float m = 0.0f;
  long i = (long)blockIdx.x * blockDim.x + threadIdx.x;
  const long stride = (long)gridDim.x * blockDim.x;
  for (; i < n4; i += stride) {
    float4 v = p[i];
    m = fmaxf(m, fmaxf(fmaxf(fabsf(v.x), fabsf(v.y)), fmaxf(fabsf(v.z), fabsf(v.w))));
  }
  for (int o = 32; o > 0; o >>= 1) m = fmaxf(m, __shfl_xor(m, o));
  if ((threadIdx.x & 63) == 0) red[threadIdx.x >> 6] = m;
  __syncthreads();
  if (threadIdx.x == 0) {
    m = fmaxf(fmaxf(red[0], red[1]), fmaxf(red[2], red[3]));
    atomicMax(slots + t, __float_as_uint(m));
  }
}

// one dispatch for all three input quantizations (blockIdx.y selects tensor).
__global__ void quant3(const float* __restrict__ in0, const float* __restrict__ in1,
                       const float* __restrict__ in2,
                       int Rp0, int Rp1, int Rp2, int R0, int R1, int R2,
                       int C0, int C1, int C2, int kt0, int kt1, int kt2,
                       const unsigned* __restrict__ slots,
                       char* __restrict__ o0, char* __restrict__ o1,
                       char* __restrict__ o2) {
  const int y = blockIdx.y;
  const float* in = (y == 0 ? in0 : (y == 1 ? in1 : in2));
  char* qout = (y == 0 ? o0 : (y == 1 ? o1 : o2));
  const int Rpad = (y == 0 ? Rp0 : (y == 1 ? Rp1 : Rp2));
  const int R = (y == 0 ? R0 : (y == 1 ? R1 : R2));
  const int C = (y == 0 ? C0 : (y == 1 ? C1 : C2));
  const int kt = (y == 0 ? kt0 : (y == 1 ? kt1 : kt2));
  const int sign = (y == 0 ? 1 : -1);
  const int segs_per_row = C >> 8;
  const int seg = blockIdx.x * 4 + (threadIdx.x >> 6);
  if (seg >= Rpad * segs_per_row) return;
  const int lane = threadIdx.x & 63;
  const int r = seg / segs_per_row;
  const int s = seg - r * segs_per_row;
  const float scale = fmaxf(__uint_as_float(slots[y]) / 7.0f, 1e-8f);
  const long n = (long)s * 256 + lane * 4;
  int mask = 0;
  unsigned pk = 0u;
  if (r < R) {
    const size_t base = (size_t)r * C + n;
    float4 v = *(const float4*)(in + base);
    int q0 = quant1(v.x, scale);
    int q1 = quant1(v.y, scale);
    int q2 = quant1(v.z, scale);
    int q3 = quant1(v.w, scale);
    pk = (q0 & 0xff) | ((q1 & 0xff) << 8) | ((q2 & 0xff) << 16) |
         ((unsigned)(q3 & 0xff) << 24);
    mask = q0 & q1 & q2 & q3 & 15;
  }
  *(unsigned*)(qout + tiled_off(r, n, kt)) = pk;
  for (int o = 32; o > 0; o >>= 1) mask &= __shfl_xor(mask, o);
  if (lane == 0)
    qout[tiled_off(r, C + s, kt)] = (char)(sign * ((mask & 7) - (mask & 8)));
  const int padw = kt * 64 - C - segs_per_row;
  if (s == 0 && lane < padw)
    qout[tiled_off(r, C + segs_per_row + lane, kt)] = 0;
}

// ---------------- GEMM core: 64x64 block, 2x2 waves of 32x32, LDS depth-1 ----
// (round-14-validated fastest config: double-buffered GLL, 16KB LDS ->
//  8 blocks/CU = 32 waves/CU). Tiled operand layout IS the LDS layout.
// MODE 0: stores gelu(acc*sc+b1) f32 (computed once) + fused block-max->pmax.
// MODE 1: split-K, stores raw acc (exact ints).
template <int MODE>
__global__ __launch_bounds__(256) void gemm_frag(
    const char* __restrict__ A, const char* __restrict__ B,
    int ktA, int mtiles, int kbase, int krem,
    i32x4* __restrict__ frag, long cslots,
    const float* __restrict__ bias, const unsigned* __restrict__ slots,
    int Mstore, float* __restrict__ pmax) {
  __shared__ char Abuf[2][4096];
  __shared__ char Bbuf[2][4096];
  const int tid = threadIdx.x;
  const int lane = tid & 63;
  const int wv = tid >> 6;

  // bijective XCD-aware swizzle (m204)
  const int nwg = gridDim.x;
  const int q8 = nwg >> 3, r8 = nwg & 7;
  const int xcd = blockIdx.x & 7, idx = blockIdx.x >> 3;
  const int sw = (xcd < r8 ? xcd * (q8 + 1) : r8 * (q8 + 1) + (xcd - r8) * q8) + idx;
  const int bm = sw % mtiles;
  const int bn = sw / mtiles;
  const long m0 = (long)bm * 64;
  const long n0 = (long)bn * 64;
  const int chunk = blockIdx.y;
  const int k_begin = chunk * kbase + min(chunk, krem);  // BK=64 tile units
  const int k_iters = kbase + (chunk < krem ? 1 : 0);

  const int wm = wv >> 1, wn = wv & 1;   // 2x2 waves of 32x32
  const int lr = lane & 15, kg = lane >> 4;

  // wave wv stages row-tile wv of the block's A and B panels
  const char* gA = A + (((long)(m0 >> 4) + wv) * ktA + k_begin) * 1024 + lane * 16;
  const char* gB = B + (((long)(n0 >> 4) + wv) * ktA + k_begin) * 1024 + lane * 16;

#define STAGE(buf, kk) do { \
    GLL(gA + (long)(kk) * 1024, (char*)Abuf + (buf) * 4096 + wv * 1024); \
    GLL(gB + (long)(kk) * 1024, (char*)Bbuf + (buf) * 4096 + wv * 1024); \
  } while (0)

  i32x4 acc[2][2] = {};

  STAGE(0, 0);
#pragma unroll 2
  for (int kt = 0; kt < k_iters; ++kt) {
    const int cur = kt & 1;
    if (kt + 1 < k_iters) {
      STAGE(cur ^ 1, kt + 1);                           // prefetch next tile
      asm volatile("s_waitcnt vmcnt(2)" ::: "memory");  // cur's 2 GLLs landed
    } else {
      asm volatile("s_waitcnt vmcnt(0)" ::: "memory");
    }
    __builtin_amdgcn_s_barrier();  // all waves' cur stages visible
    i32x4 av[2], bv[2];
#pragma unroll
    for (int f = 0; f < 2; ++f)
      av[f] = *(const i32x4*)(Abuf[cur] + (wm * 2 + f) * 1024 + lane * 16);
#pragma unroll
    for (int f = 0; f < 2; ++f)
      bv[f] = *(const i32x4*)(Bbuf[cur] + (wn * 2 + f) * 1024 + lane * 16);
#pragma unroll
    for (int fa = 0; fa < 2; ++fa)
#pragma unroll
      for (int fb = 0; fb < 2; ++fb)
        acc[fa][fb] = __builtin_amdgcn_mfma_i32_16x16x64_i8(av[fa], bv[fb], acc[fa][fb], 0, 0, 0);
    __builtin_amdgcn_s_barrier();  // reads done before buf re-staged
  }
#undef STAGE

  i32x4* po = frag + (long)chunk * cslots + (((long)sw * 4 + wv) * 4) * 64 + lane;

  if (MODE == 0) {
    __shared__ float red[4];
    const float sa = fmaxf(__uint_as_float(slots[0]) / 7.0f, 1e-8f);
    const float sb = fmaxf(__uint_as_float(slots[1]) / 7.0f, 1e-8f);
    const float sc = sa * sb;
    float bl[2];
#pragma unroll
    for (int fb = 0; fb < 2; ++fb) bl[fb] = bias[n0 + wn * 32 + fb * 16 + lr];
    float hmax = 0.0f;
#pragma unroll
    for (int fa = 0; fa < 2; ++fa) {
#pragma unroll
      for (int fb = 0; fb < 2; ++fb) {
        float4 g;
#pragma unroll
        for (int rr = 0; rr < 4; ++rr) {
          float h = gelu_exact(epi_scale((float)acc[fa][fb][rr], sc, bl[fb]));
          (&g.x)[rr] = h;
          const long m = m0 + wm * 32 + fa * 16 + kg * 4 + rr;
          if (m < Mstore) hmax = fmaxf(hmax, fabsf(h));
        }
        *(float4*)(po + (fa * 2 + fb) * 64) = g;  // gelu(h) f32, coalesced
      }
    }
    for (int o = 32; o > 0; o >>= 1) hmax = fmaxf(hmax, __shfl_xor(hmax, o));
    if ((tid & 63) == 0) red[tid >> 6] = hmax;
    __syncthreads();
    if (tid == 0)
      pmax[blockIdx.x] = fmaxf(fmaxf(red[0], red[1]), fmaxf(red[2], red[3]));
  } else {
#pragma unroll
    for (int fa = 0; fa < 2; ++fa)
#pragma unroll
      for (int fb = 0; fb < 2; ++fb)
        po[(fa * 2 + fb) * 64] = acc[fa][fb];  // raw exact-int partials
  }
}

// ---------------- fused h-quant + masks (+ pmax global reduce) --------------
// Block = (row-16-tile rt, column half). First reduces pmax[0..nb) -> sh
// (every block; identical value; block 0 publishes slots[3] for epi2frag).
// Then quantizes its 16 rows x 1536 cols of the gelu-frag into hqt bytes,
// computes per-(row,seg) AND-masks, writes corr bytes + zero tail.
__global__ __launch_bounds__(256) void quant_h(
    const float* __restrict__ gfrag, int mtiles, int Mstore,
    const float* __restrict__ pmax, int nb,
    unsigned* __restrict__ slots, char* __restrict__ hqt) {
  __shared__ unsigned char lds_m[24][16];
  __shared__ float red[4];
  const int tid = threadIdx.x;
  const int lane = tid & 63, w = tid >> 6;

  // global h-max from per-block partials
  float gm = 0.0f;
  for (int i = tid; i < nb; i += 256) gm = fmaxf(gm, pmax[i]);
  for (int o = 32; o > 0; o >>= 1) gm = fmaxf(gm, __shfl_xor(gm, o));
  if (lane == 0) red[w] = gm;
  __syncthreads();
  gm = fmaxf(fmaxf(red[0], red[1]), fmaxf(red[2], red[3]));
  if (blockIdx.x == 0 && tid == 0) slots[3] = __float_as_uint(gm);
  const float sh = fmaxf(gm / 7.0f, 1e-8f);
  __syncthreads();  // red reused? no, but lds_m writes follow; keep ordering

  const int rt = blockIdx.x >> 1;     // 0..207
  const int half = blockIdx.x & 1;    // bn 0..23 or 24..47
  const int kg = lane >> 4, lr = lane & 15;
  const int bm = rt >> 2, wm = (rt >> 1) & 1, fa = rt & 1;
  const long mrow0 = (long)rt * 16 + kg * 4;

  for (int j = 0; j < 6; ++j) {
    const int bnl = w + 4 * j;          // 0..23, bijective over (w,j)
    const int bn = half * 24 + bnl;
    int rowmask[4] = {15, 15, 15, 15};
#pragma unroll
    for (int wn = 0; wn < 2; ++wn) {
#pragma unroll
      for (int fb = 0; fb < 2; ++fb) {
        const long slot = (((long)bn * mtiles + bm) * 4 + (wm * 2 + wn)) * 4 +
                          (fa * 2 + fb);
        float4 v = ((const float4*)gfrag)[slot * 64 + lane];
#pragma unroll
        for (int rr = 0; rr < 4; ++rr) {
          const long m = mrow0 + rr;
          int q = 0;
          if (m < Mstore) q = quant1((&v.x)[rr], sh);
          hqt[((long)rt * 49 + bn) * 1024 +
              (((kg * 4 + rr) | ((wn * 2 + fb) << 4)) << 4) + lr] = (char)q;
          rowmask[rr] &= (q & 15);
        }
      }
    }
#pragma unroll
    for (int rr = 0; rr < 4; ++rr) {
      rowmask[rr] &= __shfl_xor(rowmask[rr], 1);
      rowmask[rr] &= __shfl_xor(rowmask[rr], 2);
      rowmask[rr] &= __shfl_xor(rowmask[rr], 4);
      rowmask[rr] &= __shfl_xor(rowmask[rr], 8);
    }
    if (lr == 0) {
#pragma unroll
      for (int rr = 0; rr < 4; ++rr)
        lds_m[bnl][kg * 4 + rr] = (unsigned char)rowmask[rr];
    }
  }
  __syncthreads();
  if (tid < 96) {  // 6 segs x 16 rows
    const int sl = tid >> 4, row = tid & 15;
    int m8 = lds_m[sl * 4][row] & lds_m[sl * 4 + 1][row] &
             lds_m[sl * 4 + 2][row] & lds_m[sl * 4 + 3][row] & 15;
    const int gs = half * 6 + sl;
    hqt[tiled_off((long)rt * 16 + row, 3072 + gs, 49)] =
        (char)((m8 & 7) - (m8 & 8));
  }
  if (half == 1) {  // zero tail cols [3084, 3136)
    for (int t = tid; t < 52 * 16; t += 256) {
      const int col = 3084 + (t >> 4), row = t & 15;
      hqt[tiled_off((long)rt * 16 + row, col, 49)] = 0;
    }
  }
}

// decode: fragment-slot t -> (m base, n); matches gemm_frag 64x64 geometry
struct Dec { long mb; long n; };
__device__ __forceinline__ Dec frag_decode(long t, int mtiles) {
  const int slot = (int)(t >> 10);
  const int r = (int)t & 1023;
  const int wv = r >> 8, fafb = (r >> 6) & 3, lane = r & 63;
  const int fa = fafb >> 1, fb = fafb & 1;
  const int wm = wv >> 1, wn = wv & 1;
  const int kg = lane >> 4, lr = lane & 15;
  const int bm = slot % mtiles, bn = slot / mtiles;
  Dec d;
  d.mb = (long)bm * 64 + wm * 32 + fa * 16 + kg * 4;  // rows mb..mb+3
  d.n = (long)bn * 64 + wn * 32 + fb * 16 + lr;
  return d;
}

// final epilogue: exact int sum of 4 split-K fragment chunks, scale+bias
__global__ void epi2frag(const i32x4* __restrict__ frag, long cslots, int mtiles,
                         int Mstore, const float* __restrict__ b2,
                         const unsigned* __restrict__ slots,
                         float* __restrict__ out, int ldo) {
  const long t = (long)blockIdx.x * 256 + threadIdx.x;
  if (t >= cslots) return;
  const float sa = fmaxf(__uint_as_float(slots[3]) / 7.0f, 1e-8f);
  const float sb = fmaxf(__uint_as_float(slots[2]) / 7.0f, 1e-8f);
  const float sc = sa * sb;
  Dec d = frag_decode(t, mtiles);
  i32x4 c0 = frag[t];
  i32x4 c1 = frag[t + cslots];
  i32x4 c2 = frag[t + 2 * cslots];
  i32x4 c3 = frag[t + 3 * cslots];
  const float b = b2[d.n];
#pragma unroll
  for (int rr = 0; rr < 4; ++rr) {
    const long m = d.mb + rr;
    if (m < Mstore) {
      int s = (c0[rr] + c1[rr]) + (c2[rr] + c3[rr]);  // exact ints
      out[m * (long)ldo + d.n] = epi_scale((float)s, sc, b);
    }
  }
}

// ---------------- launch -----------------------------------------------------

extern "C" void kernel_launch(void* const* d_in, const int* in_sizes, int n_in,
                              void* d_out, int out_size, void* d_ws, size_t ws_size,
                              hipStream_t stream) {
  const float* x  = (const float*)d_in[0];
  const float* w1 = (const float*)d_in[1];
  const float* b1 = (const float*)d_in[2];
  const float* w2 = (const float*)d_in[3];
  const float* b2 = (const float*)d_in[4];
  float* out = (float*)d_out;

  const int Ntok = 16 * 197;  // 3152
  const int Mpad = 3328;      // 52 tiles of 64 / 208 tiles of 16
  const int D = 768, H = 3072;
  const int KT1 = 13;         // k-tiles (64B) for D + corr
  const int KT2 = 49;         // k-tiles for H + corr
  const int SPLITK = 4;       // 49 = 4*12 + 1
  const int MT = Mpad / 64;   // 52
  const int NB1 = MT * (H / 64);                  // 2496 gemm1 blocks
  const long NF1 = (long)NB1 * 1024;              // GEMM1 fragment lanes
  const long CS2 = (long)MT * (D / 64) * 1024;    // GEMM2 slots per chunk

  char* ws = (char*)d_ws;
  size_t o = 0;
  unsigned* slots = (unsigned*)(ws + o); o += 256;  // [x, w1, w2, h]
  float* pmax = (float*)(ws + o); o += 16384;
  char* xqt  = ws + o; o += (size_t)(Mpad / 16) * KT1 * 1024;
  char* wq1t = ws + o; o += (size_t)(H / 16) * KT1 * 1024;
  char* wq2t = ws + o; o += (size_t)(D / 16) * KT2 * 1024;
  char* hqt  = ws + o; o += (size_t)(Mpad / 16) * KT2 * 1024;
  o = (o + 1023) & ~(size_t)1023;
  i32x4* frag = (i32x4*)(ws + o); o += (size_t)NF1 * 16;  // 40.9 MB, reused
  (void)ws_size; (void)in_sizes; (void)n_in; (void)out_size;

  hipLaunchKernelGGL(init_kernel, dim3(1), dim3(64), 0, stream, slots);

  hipLaunchKernelGGL(absmax3, dim3(512, 3), dim3(256), 0, stream,
                     x, (long)Ntok * D / 4, w1, (long)H * D / 4,
                     w2, (long)D * H / 4, slots);

  // one dispatch quantizes x, w1, w2 into fragment-tiled i8
  hipLaunchKernelGGL(quant3, dim3(Mpad * (D / 256) / 4, 3), dim3(256), 0, stream,
                     x, w1, w2, Mpad, H, D, Ntok, H, D, D, D, H,
                     KT1, KT1, KT2, slots, xqt, wq1t, wq2t);

  // layer 1 GEMM: depth-1 LDS pipeline (r14-fastest), gelu(h) f32 + block-max
  hipLaunchKernelGGL((gemm_frag<0>), dim3(NB1, 1), dim3(256), 0, stream,
                     xqt, wq1t, KT1, MT, KT1, 0, frag, 0L,
                     b1, slots, Ntok, pmax);

  // fused: pmax reduce + quantize gelu(h) -> hqt + masks + tail (one dispatch)
  hipLaunchKernelGGL(quant_h, dim3((Mpad / 16) * 2), dim3(256), 0, stream,
                     (const float*)frag, MT, Ntok, pmax, NB1, slots, hqt);

  // layer 2 GEMM: split-K x4, depth-1 LDS pipeline, raw int partials
  hipLaunchKernelGGL((gemm_frag<1>), dim3(MT * (D / 64), SPLITK), dim3(256), 0, stream,
                     hqt, wq2t, KT2, MT, KT2 / SPLITK, KT2 % SPLITK, frag, CS2,
                     nullptr, nullptr, 0, nullptr);

  hipLaunchKernelGGL(epi2frag, dim3((unsigned)(CS2 / 256)), dim3(256), 0, stream,
                     frag, CS2, MT, Ntok, b2, slots, out, D);
}

// Round 19
// 103.479 us; speedup vs baseline: 1.2955x; 1.1899x over previous
//
#include <hip/hip_runtime.h>
#include <hip/hip_bf16.h>
#include <stdint.h>

typedef int i32x4 __attribute__((ext_vector_type(4)));

#define GLL(gp, lp) __builtin_amdgcn_global_load_lds( \
    (const __attribute__((address_space(1))) void*)(gp), \
    (__attribute__((address_space(3))) void*)(lp), 16, 0, 0)

// ---------------- exact-math helpers (match XLA/np f32 semantics) -----------

__device__ __forceinline__ float xla_erf(float x) {
#pragma clang fp contract(off)
  x = fminf(3.832506856900711f, fmaxf(-3.832506856900711f, x));
  float x2 = x * x;
  float p = -2.72614225801306e-10f;
  p = p * x2 + 2.77068142495902e-08f;
  p = p * x2 + -2.10102402082508e-06f;
  p = p * x2 + -5.69250639462346e-05f;
  p = p * x2 + -7.34990630326855e-04f;
  p = p * x2 + -2.95459980854025e-03f;
  p = p * x2 + -1.60960333262415e-02f;
  p = x * p;
  float q = -1.45660718464996e-05f;
  q = q * x2 + -2.13374055278905e-04f;
  q = q * x2 + -1.68282697438203e-03f;
  q = q * x2 + -7.37332916720468e-03f;
  q = q * x2 + -1.42647390514189e-02f;
  return p / q;
}

__device__ __forceinline__ float gelu_exact(float x) {
#pragma clang fp contract(off)
  float t = x / 1.41421356237309504880f;
  float e = xla_erf(t);
  float u = e + 1.0f;
  float v = x * u;
  return v * 0.5f;
}

__device__ __forceinline__ float epi_scale(float iacc, float sc, float b) {
#pragma clang fp contract(off)
  float v = iacc * sc;
  v = v + b;
  return v;
}

__device__ __forceinline__ int quant1(float x, float scale) {
#pragma clang fp contract(off)
  float t = x / scale;
  t = rintf(t);
  t = fmaxf(-8.0f, fminf(7.0f, t));
  return (int)t;
}

// tiled i8 layout (round-11-validated): byte (row m, col c) at
// tile ((m>>4)*kt + (c>>6))*1024 + ((m&15) | (((c>>4)&3)<<4))*16 + (c&15)
__device__ __forceinline__ long tiled_off(long m, long c, int kt) {
  return (((m >> 4) * kt + (c >> 6)) << 10) +
         ((((m & 15) | (((c >> 4) & 3) << 4))) << 4) + (c & 15);
}

// ---------------- small kernels ---------------------------------------------

// atomic-free absmax stage 1: one partial per (tensor, block)
__global__ void absmax_part(const float* __restrict__ p0, long n0,
                            const float* __restrict__ p1, long n1,
                            const float* __restrict__ p2, long n2,
                            float* __restrict__ amax) {
  __shared__ float red[4];
  const int t = blockIdx.y;
  const float4* p = (const float4*)(t == 0 ? p0 : (t == 1 ? p1 : p2));
  const long n4 = (t == 0 ? n0 : (t == 1 ? n1 : n2));
  float m = 0.0f;
  long i = (long)blockIdx.x * blockDim.x + threadIdx.x;
  const long stride = (long)gridDim.x * blockDim.x;
  for (; i < n4; i += stride) {
    float4 v = p[i];
    m = fmaxf(m, fmaxf(fmaxf(fabsf(v.x), fabsf(v.y)), fmaxf(fabsf(v.z), fabsf(v.w))));
  }
  for (int o = 32; o > 0; o >>= 1) m = fmaxf(m, __shfl_xor(m, o));
  if ((threadIdx.x & 63) == 0) red[threadIdx.x >> 6] = m;
  __syncthreads();
  if (threadIdx.x == 0)
    amax[t * 256 + blockIdx.x] = fmaxf(fmaxf(red[0], red[1]), fmaxf(red[2], red[3]));
}

// one dispatch for all three input quantizations (blockIdx.y selects tensor).
// Opens with an atomic-free reduce of the 256 absmax partials (every block;
// block (0,y) publishes slots[y] by plain store for the GEMM epilogues).
__global__ void quant3(const float* __restrict__ in0, const float* __restrict__ in1,
                       const float* __restrict__ in2,
                       int Rp0, int Rp1, int Rp2, int R0, int R1, int R2,
                       int C0, int C1, int C2, int kt0, int kt1, int kt2,
                       const float* __restrict__ amax, unsigned* __restrict__ slots,
                       char* __restrict__ o0, char* __restrict__ o1,
                       char* __restrict__ o2) {
  __shared__ float sred[4];
  const int y = blockIdx.y;
  const int tid = threadIdx.x;
  // reduce 256 partials (all threads participate; no divergence yet)
  float gm = amax[y * 256 + tid];
  for (int o = 32; o > 0; o >>= 1) gm = fmaxf(gm, __shfl_xor(gm, o));
  if ((tid & 63) == 0) sred[tid >> 6] = gm;
  __syncthreads();
  gm = fmaxf(fmaxf(sred[0], sred[1]), fmaxf(sred[2], sred[3]));
  if (blockIdx.x == 0 && tid == 0) slots[y] = __float_as_uint(gm);
  const float scale = fmaxf(gm / 7.0f, 1e-8f);

  const float* in = (y == 0 ? in0 : (y == 1 ? in1 : in2));
  char* qout = (y == 0 ? o0 : (y == 1 ? o1 : o2));
  const int Rpad = (y == 0 ? Rp0 : (y == 1 ? Rp1 : Rp2));
  const int R = (y == 0 ? R0 : (y == 1 ? R1 : R2));
  const int C = (y == 0 ? C0 : (y == 1 ? C1 : C2));
  const int kt = (y == 0 ? kt0 : (y == 1 ? kt1 : kt2));
  const int sign = (y == 0 ? 1 : -1);
  const int segs_per_row = C >> 8;
  const int seg = blockIdx.x * 4 + (tid >> 6);
  if (seg >= Rpad * segs_per_row) return;
  const int lane = tid & 63;
  const int r = seg / segs_per_row;
  const int s = seg - r * segs_per_row;
  const long n = (long)s * 256 + lane * 4;
  int mask = 0;
  unsigned pk = 0u;
  if (r < R) {
    const size_t base = (size_t)r * C + n;
    float4 v = *(const float4*)(in + base);
    int q0 = quant1(v.x, scale);
    int q1 = quant1(v.y, scale);
    int q2 = quant1(v.z, scale);
    int q3 = quant1(v.w, scale);
    pk = (q0 & 0xff) | ((q1 & 0xff) << 8) | ((q2 & 0xff) << 16) |
         ((unsigned)(q3 & 0xff) << 24);
    mask = q0 & q1 & q2 & q3 & 15;
  }
  *(unsigned*)(qout + tiled_off(r, n, kt)) = pk;
  for (int o = 32; o > 0; o >>= 1) mask &= __shfl_xor(mask, o);
  if (lane == 0)
    qout[tiled_off(r, C + s, kt)] = (char)(sign * ((mask & 7) - (mask & 8)));
  const int padw = kt * 64 - C - segs_per_row;
  if (s == 0 && lane < padw)
    qout[tiled_off(r, C + segs_per_row + lane, kt)] = 0;
}

// ---------------- GEMM core: 64x64 block, 2x2 waves of 32x32, LDS depth-1 ----
// (round-14/18-validated fastest config: double-buffered GLL, 16KB LDS ->
//  8 blocks/CU = 32 waves/CU). Tiled operand layout IS the LDS layout.
// MODE 0: stores gelu(acc*sc+b1) f32 (computed once) + fused block-max->pmax.
// MODE 1: split-K, stores raw acc (exact ints).
template <int MODE>
__global__ __launch_bounds__(256) void gemm_frag(
    const char* __restrict__ A, const char* __restrict__ B,
    int ktA, int mtiles, int kbase, int krem,
    i32x4* __restrict__ frag, long cslots,
    const float* __restrict__ bias, const unsigned* __restrict__ slots,
    int Mstore, float* __restrict__ pmax) {
  __shared__ char Abuf[2][4096];
  __shared__ char Bbuf[2][4096];
  const int tid = threadIdx.x;
  const int lane = tid & 63;
  const int wv = tid >> 6;

  // bijective XCD-aware swizzle (m204)
  const int nwg = gridDim.x;
  const int q8 = nwg >> 3, r8 = nwg & 7;
  const int xcd = blockIdx.x & 7, idx = blockIdx.x >> 3;
  const int sw = (xcd < r8 ? xcd * (q8 + 1) : r8 * (q8 + 1) + (xcd - r8) * q8) + idx;
  const int bm = sw % mtiles;
  const int bn = sw / mtiles;
  const long m0 = (long)bm * 64;
  const long n0 = (long)bn * 64;
  const int chunk = blockIdx.y;
  const int k_begin = chunk * kbase + min(chunk, krem);  // BK=64 tile units
  const int k_iters = kbase + (chunk < krem ? 1 : 0);

  const int wm = wv >> 1, wn = wv & 1;   // 2x2 waves of 32x32
  const int lr = lane & 15, kg = lane >> 4;

  // wave wv stages row-tile wv of the block's A and B panels
  const char* gA = A + (((long)(m0 >> 4) + wv) * ktA + k_begin) * 1024 + lane * 16;
  const char* gB = B + (((long)(n0 >> 4) + wv) * ktA + k_begin) * 1024 + lane * 16;

#define STAGE(buf, kk) do { \
    GLL(gA + (long)(kk) * 1024, (char*)Abuf + (buf) * 4096 + wv * 1024); \
    GLL(gB + (long)(kk) * 1024, (char*)Bbuf + (buf) * 4096 + wv * 1024); \
  } while (0)

  i32x4 acc[2][2] = {};

  STAGE(0, 0);
#pragma unroll 2
  for (int kt = 0; kt < k_iters; ++kt) {
    const int cur = kt & 1;
    if (kt + 1 < k_iters) {
      STAGE(cur ^ 1, kt + 1);                           // prefetch next tile
      asm volatile("s_waitcnt vmcnt(2)" ::: "memory");  // cur's 2 GLLs landed
    } else {
      asm volatile("s_waitcnt vmcnt(0)" ::: "memory");
    }
    __builtin_amdgcn_s_barrier();  // all waves' cur stages visible
    i32x4 av[2], bv[2];
#pragma unroll
    for (int f = 0; f < 2; ++f)
      av[f] = *(const i32x4*)(Abuf[cur] + (wm * 2 + f) * 1024 + lane * 16);
#pragma unroll
    for (int f = 0; f < 2; ++f)
      bv[f] = *(const i32x4*)(Bbuf[cur] + (wn * 2 + f) * 1024 + lane * 16);
#pragma unroll
    for (int fa = 0; fa < 2; ++fa)
#pragma unroll
      for (int fb = 0; fb < 2; ++fb)
        acc[fa][fb] = __builtin_amdgcn_mfma_i32_16x16x64_i8(av[fa], bv[fb], acc[fa][fb], 0, 0, 0);
    __builtin_amdgcn_s_barrier();  // reads done before buf re-staged
  }
#undef STAGE

  i32x4* po = frag + (long)chunk * cslots + (((long)sw * 4 + wv) * 4) * 64 + lane;

  if (MODE == 0) {
    __shared__ float red[4];
    const float sa = fmaxf(__uint_as_float(slots[0]) / 7.0f, 1e-8f);
    const float sb = fmaxf(__uint_as_float(slots[1]) / 7.0f, 1e-8f);
    const float sc = sa * sb;
    float bl[2];
#pragma unroll
    for (int fb = 0; fb < 2; ++fb) bl[fb] = bias[n0 + wn * 32 + fb * 16 + lr];
    float hmax = 0.0f;
#pragma unroll
    for (int fa = 0; fa < 2; ++fa) {
#pragma unroll
      for (int fb = 0; fb < 2; ++fb) {
        float4 g;
#pragma unroll
        for (int rr = 0; rr < 4; ++rr) {
          float h = gelu_exact(epi_scale((float)acc[fa][fb][rr], sc, bl[fb]));
          (&g.x)[rr] = h;
          const long m = m0 + wm * 32 + fa * 16 + kg * 4 + rr;
          if (m < Mstore) hmax = fmaxf(hmax, fabsf(h));
        }
        *(float4*)(po + (fa * 2 + fb) * 64) = g;  // gelu(h) f32, coalesced
      }
    }
    for (int o = 32; o > 0; o >>= 1) hmax = fmaxf(hmax, __shfl_xor(hmax, o));
    if ((tid & 63) == 0) red[tid >> 6] = hmax;
    __syncthreads();
    if (tid == 0)
      pmax[blockIdx.x] = fmaxf(fmaxf(red[0], red[1]), fmaxf(red[2], red[3]));
  } else {
#pragma unroll
    for (int fa = 0; fa < 2; ++fa)
#pragma unroll
      for (int fb = 0; fb < 2; ++fb)
        po[(fa * 2 + fb) * 64] = acc[fa][fb];  // raw exact-int partials
  }
}

// ---------------- fused h-quant + masks (+ pmax global reduce) --------------
// Block = (row-16-tile rt, column half). First reduces pmax[0..nb) -> sh
// (every block; identical value; block 0 publishes slots[3] for epi2frag).
// Then quantizes its 16 rows x 1536 cols of the gelu-frag into hqt bytes,
// computes per-(row,seg) AND-masks, writes corr bytes + zero tail.
__global__ __launch_bounds__(256) void quant_h(
    const float* __restrict__ gfrag, int mtiles, int Mstore,
    const float* __restrict__ pmax, int nb,
    unsigned* __restrict__ slots, char* __restrict__ hqt) {
  __shared__ unsigned char lds_m[24][16];
  __shared__ float red[4];
  const int tid = threadIdx.x;
  const int lane = tid & 63, w = tid >> 6;

  // global h-max from per-block partials
  float gm = 0.0f;
  for (int i = tid; i < nb; i += 256) gm = fmaxf(gm, pmax[i]);
  for (int o = 32; o > 0; o >>= 1) gm = fmaxf(gm, __shfl_xor(gm, o));
  if (lane == 0) red[w] = gm;
  __syncthreads();
  gm = fmaxf(fmaxf(red[0], red[1]), fmaxf(red[2], red[3]));
  if (blockIdx.x == 0 && tid == 0) slots[3] = __float_as_uint(gm);
  const float sh = fmaxf(gm / 7.0f, 1e-8f);
  __syncthreads();

  const int rt = blockIdx.x >> 1;     // 0..207
  const int half = blockIdx.x & 1;    // bn 0..23 or 24..47
  const int kg = lane >> 4, lr = lane & 15;
  const int bm = rt >> 2, wm = (rt >> 1) & 1, fa = rt & 1;
  const long mrow0 = (long)rt * 16 + kg * 4;

  for (int j = 0; j < 6; ++j) {
    const int bnl = w + 4 * j;          // 0..23, bijective over (w,j)
    const int bn = half * 24 + bnl;
    int rowmask[4] = {15, 15, 15, 15};
#pragma unroll
    for (int wn = 0; wn < 2; ++wn) {
#pragma unroll
      for (int fb = 0; fb < 2; ++fb) {
        const long slot = (((long)bn * mtiles + bm) * 4 + (wm * 2 + wn)) * 4 +
                          (fa * 2 + fb);
        float4 v = ((const float4*)gfrag)[slot * 64 + lane];
#pragma unroll
        for (int rr = 0; rr < 4; ++rr) {
          const long m = mrow0 + rr;
          int q = 0;
          if (m < Mstore) q = quant1((&v.x)[rr], sh);
          hqt[((long)rt * 49 + bn) * 1024 +
              (((kg * 4 + rr) | ((wn * 2 + fb) << 4)) << 4) + lr] = (char)q;
          rowmask[rr] &= (q & 15);
        }
      }
    }
#pragma unroll
    for (int rr = 0; rr < 4; ++rr) {
      rowmask[rr] &= __shfl_xor(rowmask[rr], 1);
      rowmask[rr] &= __shfl_xor(rowmask[rr], 2);
      rowmask[rr] &= __shfl_xor(rowmask[rr], 4);
      rowmask[rr] &= __shfl_xor(rowmask[rr], 8);
    }
    if (lr == 0) {
#pragma unroll
      for (int rr = 0; rr < 4; ++rr)
        lds_m[bnl][kg * 4 + rr] = (unsigned char)rowmask[rr];
    }
  }
  __syncthreads();
  if (tid < 96) {  // 6 segs x 16 rows
    const int sl = tid >> 4, row = tid & 15;
    int m8 = lds_m[sl * 4][row] & lds_m[sl * 4 + 1][row] &
             lds_m[sl * 4 + 2][row] & lds_m[sl * 4 + 3][row] & 15;
    const int gs = half * 6 + sl;
    hqt[tiled_off((long)rt * 16 + row, 3072 + gs, 49)] =
        (char)((m8 & 7) - (m8 & 8));
  }
  if (half == 1) {  // zero tail cols [3084, 3136)
    for (int t = tid; t < 52 * 16; t += 256) {
      const int col = 3084 + (t >> 4), row = t & 15;
      hqt[tiled_off((long)rt * 16 + row, col, 49)] = 0;
    }
  }
}

// decode: fragment-slot t -> (m base, n); matches gemm_frag 64x64 geometry
struct Dec { long mb; long n; };
__device__ __forceinline__ Dec frag_decode(long t, int mtiles) {
  const int slot = (int)(t >> 10);
  const int r = (int)t & 1023;
  const int wv = r >> 8, fafb = (r >> 6) & 3, lane = r & 63;
  const int fa = fafb >> 1, fb = fafb & 1;
  const int wm = wv >> 1, wn = wv & 1;
  const int kg = lane >> 4, lr = lane & 15;
  const int bm = slot % mtiles, bn = slot / mtiles;
  Dec d;
  d.mb = (long)bm * 64 + wm * 32 + fa * 16 + kg * 4;  // rows mb..mb+3
  d.n = (long)bn * 64 + wn * 32 + fb * 16 + lr;
  return d;
}

// final epilogue: exact int sum of 4 split-K fragment chunks, scale+bias
__global__ void epi2frag(const i32x4* __restrict__ frag, long cslots, int mtiles,
                         int Mstore, const float* __restrict__ b2,
                         const unsigned* __restrict__ slots,
                         float* __restrict__ out, int ldo) {
  const long t = (long)blockIdx.x * 256 + threadIdx.x;
  if (t >= cslots) return;
  const float sa = fmaxf(__uint_as_float(slots[3]) / 7.0f, 1e-8f);
  const float sb = fmaxf(__uint_as_float(slots[2]) / 7.0f, 1e-8f);
  const float sc = sa * sb;
  Dec d = frag_decode(t, mtiles);
  i32x4 c0 = frag[t];
  i32x4 c1 = frag[t + cslots];
  i32x4 c2 = frag[t + 2 * cslots];
  i32x4 c3 = frag[t + 3 * cslots];
  const float b = b2[d.n];
#pragma unroll
  for (int rr = 0; rr < 4; ++rr) {
    const long m = d.mb + rr;
    if (m < Mstore) {
      int s = (c0[rr] + c1[rr]) + (c2[rr] + c3[rr]);  // exact ints
      out[m * (long)ldo + d.n] = epi_scale((float)s, sc, b);
    }
  }
}

// ---------------- launch -----------------------------------------------------

extern "C" void kernel_launch(void* const* d_in, const int* in_sizes, int n_in,
                              void* d_out, int out_size, void* d_ws, size_t ws_size,
                              hipStream_t stream) {
  const float* x  = (const float*)d_in[0];
  const float* w1 = (const float*)d_in[1];
  const float* b1 = (const float*)d_in[2];
  const float* w2 = (const float*)d_in[3];
  const float* b2 = (const float*)d_in[4];
  float* out = (float*)d_out;

  const int Ntok = 16 * 197;  // 3152
  const int Mpad = 3328;      // 52 tiles of 64 / 208 tiles of 16
  const int D = 768, H = 3072;
  const int KT1 = 13;         // k-tiles (64B) for D + corr
  const int KT2 = 49;         // k-tiles for H + corr
  const int SPLITK = 4;       // 49 = 4*12 + 1
  const int MT = Mpad / 64;   // 52
  const int NB1 = MT * (H / 64);                  // 2496 gemm1 blocks
  const long NF1 = (long)NB1 * 1024;              // GEMM1 fragment lanes
  const long CS2 = (long)MT * (D / 64) * 1024;    // GEMM2 slots per chunk

  char* ws = (char*)d_ws;
  size_t o = 0;
  unsigned* slots = (unsigned*)(ws + o); o += 256;  // [x, w1, w2, h]
  float* amax = (float*)(ws + o); o += 3 * 256 * 4; // input absmax partials
  float* pmax = (float*)(ws + o); o += 16384;       // gemm1 h-max partials
  char* xqt  = ws + o; o += (size_t)(Mpad / 16) * KT1 * 1024;
  char* wq1t = ws + o; o += (size_t)(H / 16) * KT1 * 1024;
  char* wq2t = ws + o; o += (size_t)(D / 16) * KT2 * 1024;
  char* hqt  = ws + o; o += (size_t)(Mpad / 16) * KT2 * 1024;
  o = (o + 1023) & ~(size_t)1023;
  i32x4* frag = (i32x4*)(ws + o); o += (size_t)NF1 * 16;  // 40.9 MB, reused
  (void)ws_size; (void)in_sizes; (void)n_in; (void)out_size;

  // stage 1 absmax: atomic-free partials (no init kernel needed anywhere)
  hipLaunchKernelGGL(absmax_part, dim3(256, 3), dim3(256), 0, stream,
                     x, (long)Ntok * D / 4, w1, (long)H * D / 4,
                     w2, (long)D * H / 4, amax);

  // one dispatch: reduce partials + quantize x, w1, w2 into fragment-tiled i8
  hipLaunchKernelGGL(quant3, dim3(Mpad * (D / 256) / 4, 3), dim3(256), 0, stream,
                     x, w1, w2, Mpad, H, D, Ntok, H, D, D, D, H,
                     KT1, KT1, KT2, amax, slots, xqt, wq1t, wq2t);

  // layer 1 GEMM: depth-1 LDS pipeline, gelu(h) f32 + block-max -> pmax
  hipLaunchKernelGGL((gemm_frag<0>), dim3(NB1, 1), dim3(256), 0, stream,
                     xqt, wq1t, KT1, MT, KT1, 0, frag, 0L,
                     b1, slots, Ntok, pmax);

  // fused: pmax reduce + quantize gelu(h) -> hqt + masks + tail (one dispatch)
  hipLaunchKernelGGL(quant_h, dim3((Mpad / 16) * 2), dim3(256), 0, stream,
                     (const float*)frag, MT, Ntok, pmax, NB1, slots, hqt);

  // layer 2 GEMM: split-K x4, depth-1 LDS pipeline, raw int partials
  hipLaunchKernelGGL((gemm_frag<1>), dim3(MT * (D / 64), SPLITK), dim3(256), 0, stream,
                     hqt, wq2t, KT2, MT, KT2 / SPLITK, KT2 % SPLITK, frag, CS2,
                     nullptr, nullptr, 0, nullptr);

  hipLaunchKernelGGL(epi2frag, dim3((unsigned)(CS2 / 256)), dim3(256), 0, stream,
                     frag, CS2, MT, Ntok, b2, slots, out, D);
}